// Round 8
// baseline (1080.283 us; speedup 1.0000x reference)
//
#include <hip/hip_runtime.h>
#include <math.h>

#define NPART 32
#define ADIM  20
#define ODIM  64
#define HID   256
#define NSTEPS 5
#define LRC   0.1f
#define NBLK  512     // 2 states per block
#define LOG33 3.4965075614664802f

typedef short bf8 __attribute__((ext_vector_type(8)));   // 8 bf16 (4 VGPRs)
typedef float f4  __attribute__((ext_vector_type(4)));   // MFMA C/D

// workspace layout (bf16 element offsets)
#define OW1T(n) ((n)*24576)             // [256 n][96 k]   w1^T, k-pad 84->96 (fwd L1 B)
#define OW2T(n) (49152 + (n)*65536)     // [256 n][256 k]  w2^T (fwd L2 B)
#define OW2C(n) (180224 + (n)*65536)    // raw w2 copy (bwd dh1 B)
#define OW1X(n) (311296 + (n)*8192)     // [32 d][256 n]   w1 act-rows, d>=20 zero (score B)
#define OW3B(n) (327680 + (n)*256)      // w3 bf16
#define WS_ELEMS 328192

__device__ __forceinline__ short f2bf(float x) {          // RNE f32->bf16 (prep only)
    unsigned u = __float_as_uint(x);
    u += 0x7FFFu + ((u >> 16) & 1u);
    return (short)(u >> 16);
}
__device__ __forceinline__ short f2bfT(float x) {         // truncating f32->bf16 (fast)
    return (short)(__float_as_uint(x) >> 16);
}
__device__ __forceinline__ float bf2f(short s) {
    return __uint_as_float(((unsigned)(unsigned short)s) << 16);
}

#define MFMA(a,b,c) __builtin_amdgcn_mfma_f32_16x16x32_bf16((a),(b),(c),0,0,0)

// ---------- prep: build bf16 weight images in ws ----------
__global__ void prep_weights(const float* __restrict__ w1a, const float* __restrict__ w2a,
                             const float* __restrict__ w3a, const float* __restrict__ w1b,
                             const float* __restrict__ w2b, const float* __restrict__ w3b,
                             unsigned short* __restrict__ ws)
{
    int idx = blockIdx.x * 256 + threadIdx.x;
    if (idx >= WS_ELEMS) return;
    float val;
    if (idx < 49152) {
        int net = idx / 24576, rem = idx % 24576;
        int n = rem / 96, k = rem % 96;
        const float* w1 = net ? w1b : w1a;
        val = (k < 84) ? w1[k*256 + n] : 0.f;
    } else if (idx < 180224) {
        int t2 = idx - 49152; int net = t2 / 65536, rem = t2 % 65536;
        int n = rem / 256, k = rem % 256;
        const float* w2 = net ? w2b : w2a;
        val = w2[k*256 + n];
    } else if (idx < 311296) {
        int t2 = idx - 180224; int net = t2 / 65536, rem = t2 % 65536;
        const float* w2 = net ? w2b : w2a;
        val = w2[rem];
    } else if (idx < 327680) {
        int t2 = idx - 311296; int net = t2 / 8192, rem = t2 % 8192;
        int d = rem / 256, n = rem % 256;
        const float* w1 = net ? w1b : w1a;
        val = (d < 20) ? w1[(64 + d)*256 + n] : 0.f;
    } else {
        int t2 = idx - 327680; int net = t2 / 256, k = t2 % 256;
        const float* w3 = net ? w3b : w3a;
        val = w3[k];
    }
    ws[idx] = (unsigned short)f2bf(val);
}

// ---------- main: 2 states/block, 512 threads ----------
// Spill-proof by construction: no MFMA accumulator is live across any
// __syncthreads() (R5-R7 spilled 0.4-1.4 GB to scratch from exactly that).
__global__ void
__attribute__((amdgpu_flat_work_group_size(512, 512), amdgpu_waves_per_eu(4, 4)))
svgd_main(const float* __restrict__ obs,  const float* __restrict__ a0g,
          const float* __restrict__ b1a,  const float* __restrict__ b2a, const float* __restrict__ b3a,
          const float* __restrict__ b1b,  const float* __restrict__ b2b, const float* __restrict__ b3b,
          const float* __restrict__ w3af, const float* __restrict__ w3bf,
          const unsigned short* __restrict__ ws, float* __restrict__ out)
{
    __shared__ __align__(16) short A0s[64*96];      // [obs|X|pad] bf16, 2 states stacked
    __shared__ __align__(16) short hbuf[64*264];    // h1 -> g1 bf16; RBF arrays alias
    __shared__ unsigned short maskH[64*16];         // relu'(z2) bits, [row][col/16]
    __shared__ float Xm[64*20];                     // fp32 master particles
    __shared__ float qpart[2][8][64];
    __shared__ int   winsS[64];
    __shared__ float logps[64];
    __shared__ unsigned short lutI[496], lutJ[496];
    __shared__ float med2[4];                        // [state][2]
    __shared__ float qvS[64];
    __shared__ float normsS[64], rowKS[64];

    // hbuf alias map (short offsets) — live only in the RBF tail of each step:
    float* d2sF = (float*)hbuf;          // shorts     0.. 4095 : d2s fp32 [2][32][32]
    float* GSF  = ((float*)hbuf) + 2048; // shorts  4096.. 8191 : X@S^T fp32 (diag = x_i·s_i)
    short* KbS  = hbuf + 8192;           // shorts  8192..10239 : K bf16 [2][32][32]
    short* SBs  = hbuf + 10240;          // shorts 10240..12287 : S bf16 [64][32] (k-pad 0)
    short* STbS = hbuf + 12288;          // shorts 12288..14335 : S^T bf16 [2][32dd][32j]
    short* XTbS = hbuf + 14336;          // shorts 14336..16383 : X^T bf16 [2][32dd][32j]

    const int t = threadIdx.x, b = blockIdx.x;
    const int lane = t & 63, wv = t >> 6;           // 8 waves
    const int q = lane >> 4, mp = lane & 15;
    const int nb = wv * 32;                          // 32-col slice of the 256-wide GEMMs

    // ---- init ----
    for (int p = t; p < 64*ODIM; p += 512) {
        int i = p >> 6, d = p & 63;
        A0s[i*96 + d] = f2bfT(obs[(b*64 + i)*ODIM + d]);
    }
    for (int p = t; p < 64*ADIM; p += 512) {
        int i = p / 20, d = p - i*20;
        float v = a0g[(b*64 + i)*20 + d];
        Xm[p] = v;
        A0s[i*96 + 64 + d] = f2bfT(v);
    }
    for (int p = t; p < 64*12; p += 512) { int i = p/12, d = p - i*12; A0s[i*96 + 84 + d] = 0; }
    if (t < 496) {
        int i_ = 0, rem = t;
        while (rem >= 31 - i_) { rem -= 31 - i_; ++i_; }
        lutI[t] = (unsigned short)i_; lutJ[t] = (unsigned short)(i_ + 1 + rem);
    }
    if (t < 64) logps[t] = 0.f;
    __syncthreads();

    const int mt = wv & 3, ch = wv >> 2;             // score tile mapping

    for (int step = 0; step < NSTEPS; ++step) {
        f4 sa0 = (f4){0,0,0,0}, sa1 = (f4){0,0,0,0}; // per-net ungated score frags

        #pragma unroll
        for (int net = 0; net < 2; ++net) {
            const unsigned short* w1t  = ws + OW1T(net);
            const unsigned short* w2t  = ws + OW2T(net);
            const unsigned short* w2c  = ws + OW2C(net);
            const unsigned short* w1x  = ws + OW1X(net);
            const unsigned short* w3b8 = ws + OW3B(net);
            const float* b1p = net ? b1b : b1a;
            const float* b2p = net ? b2b : b2a;
            const float* w3p = net ? w3bf : w3af;
            unsigned m0reg;                           // relu-L1 bits (h*8+s*4+r)

            // ---- fwd L1: [64x96] @ w1t -> h1 ----
            {
                f4 acc[4][2];
                #pragma unroll
                for (int h = 0; h < 4; ++h) { acc[h][0] = (f4){0,0,0,0}; acc[h][1] = (f4){0,0,0,0}; }
                #pragma unroll
                for (int k0 = 0; k0 < 96; k0 += 32) {
                    bf8 bb0 = *(const bf8*)(w1t + (size_t)(nb +      mp)*96 + k0 + q*8);
                    bf8 bb1 = *(const bf8*)(w1t + (size_t)(nb + 16 + mp)*96 + k0 + q*8);
                    #pragma unroll
                    for (int h = 0; h < 4; ++h) {
                        bf8 aa = *(const bf8*)&A0s[(h*16 + mp)*96 + k0 + q*8];
                        acc[h][0] = MFMA(aa, bb0, acc[h][0]);
                        acc[h][1] = MFMA(aa, bb1, acc[h][1]);
                    }
                }
                unsigned mbits = 0u;
                #pragma unroll
                for (int h = 0; h < 4; ++h) {
                    #pragma unroll
                    for (int s = 0; s < 2; ++s) {
                        int col = nb + s*16 + mp;
                        float bias = b1p[col];
                        #pragma unroll
                        for (int r = 0; r < 4; ++r) {
                            float v = acc[h][s][r] + bias;
                            bool pos = v > 0.f;
                            if (pos) mbits |= 1u << (h*8 + s*4 + r);
                            hbuf[(h*16 + q*4 + r)*264 + col] = f2bfT(pos ? v : 0.f);
                        }
                    }
                }
                m0reg = mbits;
            }
            __syncthreads();                          // B1: h1 ready

            // ---- fwd L2: h1 @ w2t ; epi: qpart + relu' bits -> maskH ----
            {
                f4 acc[4][2];
                #pragma unroll
                for (int h = 0; h < 4; ++h) { acc[h][0] = (f4){0,0,0,0}; acc[h][1] = (f4){0,0,0,0}; }
                #pragma unroll
                for (int k0 = 0; k0 < 256; k0 += 32) {
                    bf8 bb0 = *(const bf8*)(w2t + (size_t)(nb +      mp)*256 + k0 + q*8);
                    bf8 bb1 = *(const bf8*)(w2t + (size_t)(nb + 16 + mp)*256 + k0 + q*8);
                    #pragma unroll
                    for (int h = 0; h < 4; ++h) {
                        bf8 aa = *(const bf8*)&hbuf[(h*16 + mp)*264 + k0 + q*8];
                        acc[h][0] = MFMA(aa, bb0, acc[h][0]);
                        acc[h][1] = MFMA(aa, bb1, acc[h][1]);
                    }
                }
                float qp[4][4] = {{0,0,0,0},{0,0,0,0},{0,0,0,0},{0,0,0,0}};
                #pragma unroll
                for (int h = 0; h < 4; ++h) {
                    #pragma unroll
                    for (int s = 0; s < 2; ++s) {
                        int col = nb + s*16 + mp;
                        float bias = b2p[col], w3v = w3p[col];
                        #pragma unroll
                        for (int r = 0; r < 4; ++r) {
                            float v = acc[h][s][r] + bias;
                            bool pos = v > 0.f;
                            unsigned long long bal = __ballot(pos);
                            if (mp == 0)    // halfword overwrite: no atomics, no zeroing
                                maskH[(h*16 + q*4 + r)*16 + 2*wv + s] =
                                    (unsigned short)((bal >> (q*16)) & 0xFFFFull);
                            qp[h][r] += pos ? v * w3v : 0.f;
                        }
                    }
                }
                #pragma unroll
                for (int d = 1; d < 16; d <<= 1)
                    #pragma unroll
                    for (int h = 0; h < 4; ++h)
                        #pragma unroll
                        for (int r = 0; r < 4; ++r)
                            qp[h][r] += __shfl_xor(qp[h][r], d, 64);
                if (mp == 0) {
                    #pragma unroll
                    for (int h = 0; h < 4; ++h)
                        #pragma unroll
                        for (int r = 0; r < 4; ++r)
                            qpart[net][wv][h*16 + q*4 + r] = qp[h][r];
                }
            }
            __syncthreads();                          // B2: h1 reads done; maskH+qpart visible

            // ---- bwd dh1: A rebuilt from maskH x w3 (no hbuf reads!); g1 over dead h1 ----
            {
                f4 accB[4][2];
                #pragma unroll
                for (int h = 0; h < 4; ++h) { accB[h][0] = (f4){0,0,0,0}; accB[h][1] = (f4){0,0,0,0}; }
                #pragma unroll
                for (int k0 = 0; k0 < 256; k0 += 32) {
                    bf8 w3v = *(const bf8*)(w3b8 + k0 + q*8);
                    bf8 c0 = *(const bf8*)(w2c + (size_t)(nb +      mp)*256 + k0 + q*8);
                    bf8 c1 = *(const bf8*)(w2c + (size_t)(nb + 16 + mp)*256 + k0 + q*8);
                    #pragma unroll
                    for (int h = 0; h < 4; ++h) {
                        unsigned bits = ((unsigned)maskH[(h*16 + mp)*16 + (k0 >> 4) + (q >> 1)]
                                         >> ((q & 1)*8)) & 0xFFu;
                        bf8 aa;
                        #pragma unroll
                        for (int j = 0; j < 8; ++j)
                            aa[j] = ((bits >> j) & 1u) ? w3v[j] : (short)0;
                        accB[h][0] = MFMA(aa, c0, accB[h][0]);
                        accB[h][1] = MFMA(aa, c1, accB[h][1]);
                    }
                }
                // epi (no barrier since B2 — h1 dead, nobody reads hbuf in this phase)
                #pragma unroll
                for (int h = 0; h < 4; ++h) {
                    #pragma unroll
                    for (int s = 0; s < 2; ++s) {
                        int col = nb + s*16 + mp;
                        #pragma unroll
                        for (int r = 0; r < 4; ++r) {
                            bool on = (m0reg >> (h*8 + s*4 + r)) & 1u;
                            hbuf[(h*16 + q*4 + r)*264 + col] = f2bfT(on ? accB[h][s][r] : 0.f);
                        }
                    }
                }
                if (net == 1 && t < 64) {             // argmin (both qpart sets ready)
                    float q0 = b3a[0], q1 = b3b[0];
                    #pragma unroll
                    for (int w = 0; w < 8; ++w) { q0 += qpart[0][w][t]; q1 += qpart[1][w][t]; }
                    winsS[t] = (q0 <= q1) ? 0 : 1;
                }
            }
            __syncthreads();                          // B3: g1 (+ winsS) ready

            // ---- score (ungated rows): g1 @ w1x ----
            {
                f4 sa = (f4){0,0,0,0};
                #pragma unroll
                for (int k0 = 0; k0 < 256; k0 += 32) {
                    bf8 bx = *(const bf8*)(w1x + (size_t)(ch*16 + mp)*256 + k0 + q*8);
                    bf8 aa = *(const bf8*)&hbuf[(mt*16 + mp)*264 + k0 + q*8];
                    sa = MFMA(aa, bx, sa);
                }
                if (net == 0) sa0 = sa; else sa1 = sa;
            }
            __syncthreads();                          // B4: g1 reads done
        } // net

        // ---- row-gated score select + S shadows; XT + norms ----
        {
            int colD = ch*16 + mp;               // 0..31 (cols >=20 exact zeros)
            #pragma unroll
            for (int r = 0; r < 4; ++r) {
                int row = mt*16 + q*4 + r, st = row >> 5, il = row & 31;
                float sv = winsS[row] ? sa1[r] : sa0[r];
                short sb = f2bfT(sv);
                SBs[row*32 + colD] = sb;
                STbS[st*1024 + colD*32 + il] = sb;
            }
        }
        if (t < 64) {
            int st = t >> 5, il = t & 31;
            float nrm = 0.f;
            #pragma unroll
            for (int d = 0; d < 20; ++d) {
                float xb = bf2f(A0s[t*96 + 64 + d]);
                nrm += xb * xb;
                XTbS[st*1024 + d*32 + il] = f2bfT(Xm[t*20 + d]);
            }
            #pragma unroll
            for (int d = 20; d < 32; ++d) XTbS[st*1024 + d*32 + il] = 0;
            normsS[t] = nrm;
        }
        __syncthreads();

        // ---- Gram: d2s = n_i+n_j-2*XX^T ; GS = X S^T ----
        {
            int stw = wv >> 2, mtl = (wv >> 1) & 1, ntl = wv & 1;
            bf8 aa  = *(const bf8*)&A0s[(stw*32 + mtl*16 + mp)*96 + 64 + q*8];
            bf8 bbx = *(const bf8*)&A0s[(stw*32 + ntl*16 + mp)*96 + 64 + q*8];
            bf8 bbs = *(const bf8*)&SBs[(stw*32 + ntl*16 + mp)*32 + q*8];
            f4 gx = MFMA(aa, bbx, ((f4){0,0,0,0}));
            f4 gs = MFMA(aa, bbs, ((f4){0,0,0,0}));
            int jl = ntl*16 + mp;
            float nj = normsS[stw*32 + jl];
            #pragma unroll
            for (int r = 0; r < 4; ++r) {
                int il = mtl*16 + q*4 + r;
                d2sF[stw*1024 + il*32 + jl] = normsS[stw*32 + il] + nj - 2.f*gx[r];
                GSF [stw*1024 + il*32 + jl] = gs[r];
            }
        }
        __syncthreads();

        // ---- median sort (waves 0-1, in-register bitonic) ----
        if (wv < 2) {
            const float* base = d2sF + wv*1024;
            float v[8];
            #pragma unroll
            for (int i = 0; i < 8; ++i) {
                int e = lane*8 + i;
                v[i] = (e < 496) ? base[lutI[e]*32 + lutJ[e]] : 3.4e38f;
            }
            for (int k = 2; k <= 512; k <<= 1) {
                for (int jj = k >> 1; jj >= 8; jj >>= 1) {
                    int lm = jj >> 3;
                    #pragma unroll
                    for (int i = 0; i < 8; ++i) {
                        float w = __shfl_xor(v[i], lm, 64);
                        int p = lane*8 + i;
                        bool takeMin = (((p & k) == 0) == ((p & jj) == 0));
                        v[i] = takeMin ? fminf(v[i], w) : fmaxf(v[i], w);
                    }
                }
                int jj0 = (k >> 1) < 4 ? (k >> 1) : 4;
                for (int jj = jj0; jj >= 1; jj >>= 1) {
                    #pragma unroll
                    for (int i = 0; i < 8; ++i) {
                        if ((i & jj) == 0) {
                            int i2 = i | jj;
                            int p = lane*8 + i;
                            bool up = ((p & k) == 0);
                            float x = v[i], y = v[i2];
                            float mn = fminf(x, y), mx = fmaxf(x, y);
                            v[i] = up ? mn : mx; v[i2] = up ? mx : mn;
                        }
                    }
                }
            }
            if (lane == 29) med2[wv*2 + 0] = v[7];   // sorted index 239
            if (lane == 30) med2[wv*2 + 1] = v[0];   // sorted index 240
        }
        __syncthreads();

        // ---- K = exp(-g d2), logp row-terms, rowK ----
        {
            int i = t >> 3, stw = i >> 5, il = i & 31, j0 = (t & 7) * 4;
            float medv = 0.5f * (med2[stw*2] + med2[stw*2 + 1]);
            float gam  = 1.f / (2.f * (medv / (2.f * LOG33)) + 1e-8f);
            float sK = 0.f, sKGS = 0.f, sKd2 = 0.f, sKdg = 0.f;
            #pragma unroll
            for (int jj = 0; jj < 4; ++jj) {
                int j = j0 + jj;
                float d2 = d2sF[stw*1024 + il*32 + j];
                float K  = expf(-gam * d2);
                KbS[stw*1024 + il*32 + j] = f2bfT(K);
                sK   += K;
                sKGS += K * GSF[stw*1024 + il*32 + j];
                sKd2 += K * d2;
                sKdg += K * GSF[stw*1024 + j*32 + j];   // diag GS_jj = x_j·s_j
            }
            #pragma unroll
            for (int d = 1; d < 8; d <<= 1) {
                sK   += __shfl_xor(sK,   d, 64);
                sKGS += __shfl_xor(sKGS, d, 64);
                sKd2 += __shfl_xor(sKd2, d, 64);
                sKdg += __shfl_xor(sKdg, d, 64);
            }
            if ((t & 7) == 0) {
                rowKS[i] = sK;
                float sdots = sKGS - sKdg;
                float ssum  = -2.f*gam*sdots
                              - 2.f*gam*(2.f*gam*sKd2 - 20.f*(sK - 1.f));
                logps[i] -= LRC * (ssum * (1.f/32.f));
            }
        }
        __syncthreads();

        // ---- phi = (K@S + 2g(x*rowK - K@X))/32 ; X += LR*phi ----
        {
            int stw = wv >> 2, mtl = (wv >> 1) & 1, ntl = wv & 1;
            float medv = 0.5f * (med2[stw*2] + med2[stw*2 + 1]);
            float gam  = 1.f / (2.f * (medv / (2.f * LOG33)) + 1e-8f);
            bf8 aa  = *(const bf8*)&KbS [stw*1024 + (mtl*16 + mp)*32 + q*8];
            bf8 b1v = *(const bf8*)&STbS[stw*1024 + (ntl*16 + mp)*32 + q*8];
            bf8 b2v = *(const bf8*)&XTbS[stw*1024 + (ntl*16 + mp)*32 + q*8];
            f4 ks = MFMA(aa, b1v, ((f4){0,0,0,0}));
            f4 kx = MFMA(aa, b2v, ((f4){0,0,0,0}));
            int dd = ntl*16 + mp;
            if (dd < 20) {
                #pragma unroll
                for (int r = 0; r < 4; ++r) {
                    int gi = stw*32 + mtl*16 + q*4 + r;
                    float xi  = Xm[gi*20 + dd];
                    float phi = (ks[r] + 2.f*gam*(xi*rowKS[gi] - kx[r])) * (1.f/32.f);
                    float nx  = xi + LRC * phi;
                    Xm[gi*20 + dd] = nx;
                    A0s[gi*96 + 64 + dd] = f2bfT(nx);
                }
            }
        }
        __syncthreads();
    } // steps

    // ================= epilogue =================
    for (int p = t; p < 64*20; p += 512) {
        int i = p / 20, d = p - i*20;
        out[(b*64 + i)*20 + d] = tanhf(Xm[p]);
    }
    if (t < 64) {
        float lt = 0.f, s0 = 0.f;
        for (int d = 0; d < 20; ++d) {
            float a  = Xm[t*20 + d];
            float x  = -2.f * a;
            float sp = fmaxf(x, 0.f) + log1pf(expf(-fabsf(x)));
            lt -= 2.f * (0.69314718056f - a - sp);
            float v = a0g[(b*64 + t)*20 + d];
            s0 += v * v;
        }
        qvS[t] = -18.3787706641f - 0.5f*s0 + logps[t] + lt;
    }
    __syncthreads();
    if (t < 2) {
        float s = 0.f;
        for (int i = 0; i < 32; ++i) s += qvS[t*32 + i];
        out[1024*32*20 + b*2 + t] = s * (1.f/32.f);
    }
}

extern "C" void kernel_launch(void* const* d_in, const int* in_sizes, int n_in,
                              void* d_out, int out_size, void* d_ws, size_t ws_size,
                              hipStream_t stream) {
    unsigned short* ws = (unsigned short*)d_ws;
    prep_weights<<<(WS_ELEMS + 255)/256, 256, 0, stream>>>(
        (const float*)d_in[2],  (const float*)d_in[4],  (const float*)d_in[6],
        (const float*)d_in[8],  (const float*)d_in[10], (const float*)d_in[12], ws);
    svgd_main<<<NBLK, 512, 0, stream>>>(
        (const float*)d_in[0],  (const float*)d_in[1],
        (const float*)d_in[3],  (const float*)d_in[5],  (const float*)d_in[7],
        (const float*)d_in[9],  (const float*)d_in[11], (const float*)d_in[13],
        (const float*)d_in[6],  (const float*)d_in[12],
        ws, (float*)d_out);
}

// Round 9
// 511.688 us; speedup vs baseline: 2.1112x; 2.1112x over previous
//
#include <hip/hip_runtime.h>
#include <math.h>

#define NPART 32
#define ADIM  20
#define ODIM  64
#define HID   256
#define NSTEPS 5
#define LRC   0.1f
#define NBLK  512     // 2 states per block
#define LOG33 3.4965075614664802f

typedef short bf8 __attribute__((ext_vector_type(8)));   // 8 bf16 (4 VGPRs)
typedef float f4  __attribute__((ext_vector_type(4)));   // MFMA C/D

// workspace layout (bf16 element offsets)
#define OW1T(n) ((n)*24576)             // [256 n][96 k]   w1^T, k-pad 84->96 (fwd L1 B)
#define OW2T(n) (49152 + (n)*65536)     // [256 n][256 k]  w2^T (fwd L2 B)
#define OW2C(n) (180224 + (n)*65536)    // raw w2 copy (bwd dh1 B)
#define OW1X(n) (311296 + (n)*8192)     // [32 d][256 n]   w1 act-rows, d>=20 zero (score B)
#define OW3B(n) (327680 + (n)*256)      // w3 bf16
#define WS_ELEMS 328192

__device__ __forceinline__ short f2bf(float x) {          // RNE f32->bf16 (prep only)
    unsigned u = __float_as_uint(x);
    u += 0x7FFFu + ((u >> 16) & 1u);
    return (short)(u >> 16);
}
__device__ __forceinline__ short f2bfT(float x) {         // truncating f32->bf16 (fast)
    return (short)(__float_as_uint(x) >> 16);
}
__device__ __forceinline__ float bf2f(short s) {
    return __uint_as_float(((unsigned)(unsigned short)s) << 16);
}

#define MFMA(a,b,c) __builtin_amdgcn_mfma_f32_16x16x32_bf16((a),(b),(c),0,0,0)

// ---------- prep: build bf16 weight images in ws ----------
__global__ void prep_weights(const float* __restrict__ w1a, const float* __restrict__ w2a,
                             const float* __restrict__ w3a, const float* __restrict__ w1b,
                             const float* __restrict__ w2b, const float* __restrict__ w3b,
                             unsigned short* __restrict__ ws)
{
    int idx = blockIdx.x * 256 + threadIdx.x;
    if (idx >= WS_ELEMS) return;
    float val;
    if (idx < 49152) {
        int net = idx / 24576, rem = idx % 24576;
        int n = rem / 96, k = rem % 96;
        const float* w1 = net ? w1b : w1a;
        val = (k < 84) ? w1[k*256 + n] : 0.f;
    } else if (idx < 180224) {
        int t2 = idx - 49152; int net = t2 / 65536, rem = t2 % 65536;
        int n = rem / 256, k = rem % 256;
        const float* w2 = net ? w2b : w2a;
        val = w2[k*256 + n];
    } else if (idx < 311296) {
        int t2 = idx - 180224; int net = t2 / 65536, rem = t2 % 65536;
        const float* w2 = net ? w2b : w2a;
        val = w2[rem];
    } else if (idx < 327680) {
        int t2 = idx - 311296; int net = t2 / 8192, rem = t2 % 8192;
        int d = rem / 256, n = rem % 256;
        const float* w1 = net ? w1b : w1a;
        val = (d < 20) ? w1[(64 + d)*256 + n] : 0.f;
    } else {
        int t2 = idx - 327680; int net = t2 / 256, k = t2 % 256;
        const float* w3 = net ? w3b : w3a;
        val = w3[k];
    }
    ws[idx] = (unsigned short)f2bf(val);
}

// ---------- main: 2 states/block, 512 threads ----------
// Spill discipline (R8 post-mortem): every 8-iteration K-loop over global
// B-fragments is `#pragma unroll 1` + manual 2-deep prefetch. Full unroll lets
// the compiler hoist up to 64 VGPRs of loads -> in-loop acc spill at the
// 64-VGPR allocation (R5-R8: 0.4-1.4 GB phantom scratch traffic).
__global__ void __launch_bounds__(512, 4)
svgd_main(const float* __restrict__ obs,  const float* __restrict__ a0g,
          const float* __restrict__ b1a,  const float* __restrict__ b2a, const float* __restrict__ b3a,
          const float* __restrict__ b1b,  const float* __restrict__ b2b, const float* __restrict__ b3b,
          const float* __restrict__ w3af, const float* __restrict__ w3bf,
          const unsigned short* __restrict__ ws, float* __restrict__ out)
{
    __shared__ __align__(16) short A0s[64*96];      // [obs|X|pad] bf16, 2 states stacked
    __shared__ __align__(16) short hbuf[64*264];    // h1 -> g1 bf16; RBF arrays alias
    __shared__ unsigned short maskH[64*16];         // relu'(z2) bits, [row][col/16]
    __shared__ float Xm[64*20];                     // fp32 master particles
    __shared__ float qpart[2][8][64];
    __shared__ int   winsS[64];
    __shared__ float logps[64];
    __shared__ unsigned short lutI[496], lutJ[496];
    __shared__ float med2[4];                        // [state][2]
    __shared__ float qvS[64];
    __shared__ float normsS[64], rowKS[64];

    // hbuf alias map (short offsets) — live only in the RBF tail of each step:
    float* d2sF = (float*)hbuf;          // shorts     0.. 4095 : d2s fp32 [2][32][32]
    float* GSF  = ((float*)hbuf) + 2048; // shorts  4096.. 8191 : X@S^T fp32 (diag = x_i·s_i)
    short* KbS  = hbuf + 8192;           // shorts  8192..10239 : K bf16 [2][32][32]
    short* SBs  = hbuf + 10240;          // shorts 10240..12287 : S bf16 [64][32] (k-pad 0)
    short* STbS = hbuf + 12288;          // shorts 12288..14335 : S^T bf16 [2][32dd][32j]
    short* XTbS = hbuf + 14336;          // shorts 14336..16383 : X^T bf16 [2][32dd][32j]

    const int t = threadIdx.x, b = blockIdx.x;
    const int lane = t & 63, wv = t >> 6;           // 8 waves
    const int q = lane >> 4, mp = lane & 15;
    const int nb = wv * 32;                          // 32-col slice of the 256-wide GEMMs

    // ---- init ----
    for (int p = t; p < 64*ODIM; p += 512) {
        int i = p >> 6, d = p & 63;
        A0s[i*96 + d] = f2bfT(obs[(b*64 + i)*ODIM + d]);
    }
    for (int p = t; p < 64*ADIM; p += 512) {
        int i = p / 20, d = p - i*20;
        float v = a0g[(b*64 + i)*20 + d];
        Xm[p] = v;
        A0s[i*96 + 64 + d] = f2bfT(v);
    }
    for (int p = t; p < 64*12; p += 512) { int i = p/12, d = p - i*12; A0s[i*96 + 84 + d] = 0; }
    if (t < 496) {
        int i_ = 0, rem = t;
        while (rem >= 31 - i_) { rem -= 31 - i_; ++i_; }
        lutI[t] = (unsigned short)i_; lutJ[t] = (unsigned short)(i_ + 1 + rem);
    }
    if (t < 64) logps[t] = 0.f;
    __syncthreads();

    const int mt = wv & 3, ch = wv >> 2;             // score tile mapping

    for (int step = 0; step < NSTEPS; ++step) {
        f4 sa0 = (f4){0,0,0,0}, sa1 = (f4){0,0,0,0}; // per-net ungated score frags

        #pragma unroll
        for (int net = 0; net < 2; ++net) {
            const unsigned short* w1t  = ws + OW1T(net);
            const unsigned short* w2t  = ws + OW2T(net);
            const unsigned short* w2c  = ws + OW2C(net);
            const unsigned short* w1x  = ws + OW1X(net);
            const unsigned short* w3b8 = ws + OW3B(net);
            const float* b1p = net ? b1b : b1a;
            const float* b2p = net ? b2b : b2a;
            const float* w3p = net ? w3bf : w3af;
            unsigned m0reg;                           // relu-L1 bits (h*8+s*4+r)

            // ---- fwd L1: [64x96] @ w1t -> h1 (3-iter K-loop, manual dbuf) ----
            {
                f4 acc[4][2];
                #pragma unroll
                for (int h = 0; h < 4; ++h) { acc[h][0] = (f4){0,0,0,0}; acc[h][1] = (f4){0,0,0,0}; }
                const unsigned short* bp0 = w1t + (size_t)(nb +      mp)*96 + q*8;
                const unsigned short* bp1 = w1t + (size_t)(nb + 16 + mp)*96 + q*8;
                bf8 bb0 = *(const bf8*)bp0, bb1 = *(const bf8*)bp1;
                #pragma unroll 1
                for (int k0 = 0; k0 < 96; k0 += 32) {
                    bf8 n0 = bb0, n1 = bb1;
                    if (k0 + 32 < 96) { n0 = *(const bf8*)(bp0 + k0 + 32); n1 = *(const bf8*)(bp1 + k0 + 32); }
                    #pragma unroll
                    for (int h = 0; h < 4; ++h) {
                        bf8 aa = *(const bf8*)&A0s[(h*16 + mp)*96 + k0 + q*8];
                        acc[h][0] = MFMA(aa, bb0, acc[h][0]);
                        acc[h][1] = MFMA(aa, bb1, acc[h][1]);
                    }
                    bb0 = n0; bb1 = n1;
                }
                unsigned mbits = 0u;
                #pragma unroll
                for (int h = 0; h < 4; ++h) {
                    #pragma unroll
                    for (int s = 0; s < 2; ++s) {
                        int col = nb + s*16 + mp;
                        float bias = b1p[col];
                        #pragma unroll
                        for (int r = 0; r < 4; ++r) {
                            float v = acc[h][s][r] + bias;
                            bool pos = v > 0.f;
                            if (pos) mbits |= 1u << (h*8 + s*4 + r);
                            hbuf[(h*16 + q*4 + r)*264 + col] = f2bfT(pos ? v : 0.f);
                        }
                    }
                }
                m0reg = mbits;
            }
            __syncthreads();                          // B1: h1 ready

            // ---- fwd L2: h1 @ w2t (8-iter K-loop, unroll 1 + dbuf) ----
            {
                f4 acc[4][2];
                #pragma unroll
                for (int h = 0; h < 4; ++h) { acc[h][0] = (f4){0,0,0,0}; acc[h][1] = (f4){0,0,0,0}; }
                const unsigned short* bp0 = w2t + (size_t)(nb +      mp)*256 + q*8;
                const unsigned short* bp1 = w2t + (size_t)(nb + 16 + mp)*256 + q*8;
                bf8 bb0 = *(const bf8*)bp0, bb1 = *(const bf8*)bp1;
                #pragma unroll 1
                for (int k0 = 0; k0 < 256; k0 += 32) {
                    bf8 n0 = bb0, n1 = bb1;
                    if (k0 + 32 < 256) { n0 = *(const bf8*)(bp0 + k0 + 32); n1 = *(const bf8*)(bp1 + k0 + 32); }
                    #pragma unroll
                    for (int h = 0; h < 4; ++h) {
                        bf8 aa = *(const bf8*)&hbuf[(h*16 + mp)*264 + k0 + q*8];
                        acc[h][0] = MFMA(aa, bb0, acc[h][0]);
                        acc[h][1] = MFMA(aa, bb1, acc[h][1]);
                    }
                    bb0 = n0; bb1 = n1;
                }
                // epi: ballots -> maskH halfwords (overwrite), qp reduce -> qpart
                float qp[4][4] = {{0,0,0,0},{0,0,0,0},{0,0,0,0},{0,0,0,0}};
                #pragma unroll
                for (int h = 0; h < 4; ++h) {
                    #pragma unroll
                    for (int s = 0; s < 2; ++s) {
                        int col = nb + s*16 + mp;
                        float bias = b2p[col], w3v = w3p[col];
                        #pragma unroll
                        for (int r = 0; r < 4; ++r) {
                            float v = acc[h][s][r] + bias;
                            bool pos = v > 0.f;
                            unsigned long long bal = __ballot(pos);
                            if (mp == 0)
                                maskH[(h*16 + q*4 + r)*16 + 2*wv + s] =
                                    (unsigned short)((bal >> (q*16)) & 0xFFFFull);
                            qp[h][r] += pos ? v * w3v : 0.f;
                        }
                    }
                }
                #pragma unroll
                for (int d = 1; d < 16; d <<= 1)
                    #pragma unroll
                    for (int h = 0; h < 4; ++h)
                        #pragma unroll
                        for (int r = 0; r < 4; ++r)
                            qp[h][r] += __shfl_xor(qp[h][r], d, 64);
                if (mp == 0) {
                    #pragma unroll
                    for (int h = 0; h < 4; ++h)
                        #pragma unroll
                        for (int r = 0; r < 4; ++r)
                            qpart[net][wv][h*16 + q*4 + r] = qp[h][r];
                }
            }
            __syncthreads();                          // B2: h1 reads done; maskH+qpart visible

            // ---- bwd dh1: A from maskH x w3 (no hbuf reads); g1 over dead h1 ----
            {
                f4 accB[4][2];
                #pragma unroll
                for (int h = 0; h < 4; ++h) { accB[h][0] = (f4){0,0,0,0}; accB[h][1] = (f4){0,0,0,0}; }
                const unsigned short* cp0 = w2c + (size_t)(nb +      mp)*256 + q*8;
                const unsigned short* cp1 = w2c + (size_t)(nb + 16 + mp)*256 + q*8;
                bf8 c0 = *(const bf8*)cp0, c1 = *(const bf8*)cp1;
                bf8 w3v = *(const bf8*)(w3b8 + q*8);
                #pragma unroll 1
                for (int k0 = 0; k0 < 256; k0 += 32) {
                    bf8 nc0 = c0, nc1 = c1, nw = w3v;
                    if (k0 + 32 < 256) {
                        nc0 = *(const bf8*)(cp0 + k0 + 32);
                        nc1 = *(const bf8*)(cp1 + k0 + 32);
                        nw  = *(const bf8*)(w3b8 + k0 + 32 + q*8);
                    }
                    #pragma unroll
                    for (int h = 0; h < 4; ++h) {
                        unsigned bits = ((unsigned)maskH[(h*16 + mp)*16 + (k0 >> 4) + (q >> 1)]
                                         >> ((q & 1)*8)) & 0xFFu;
                        bf8 aa;
                        #pragma unroll
                        for (int j = 0; j < 8; ++j)
                            aa[j] = ((bits >> j) & 1u) ? w3v[j] : (short)0;
                        accB[h][0] = MFMA(aa, c0, accB[h][0]);
                        accB[h][1] = MFMA(aa, c1, accB[h][1]);
                    }
                    c0 = nc0; c1 = nc1; w3v = nw;
                }
                // epi: g1 = dh1 * mask0 over dead h1 (no barrier needed since B2)
                #pragma unroll
                for (int h = 0; h < 4; ++h) {
                    #pragma unroll
                    for (int s = 0; s < 2; ++s) {
                        int col = nb + s*16 + mp;
                        #pragma unroll
                        for (int r = 0; r < 4; ++r) {
                            bool on = (m0reg >> (h*8 + s*4 + r)) & 1u;
                            hbuf[(h*16 + q*4 + r)*264 + col] = f2bfT(on ? accB[h][s][r] : 0.f);
                        }
                    }
                }
                if (net == 1 && t < 64) {             // argmin (both qpart sets ready)
                    float q0 = b3a[0], q1 = b3b[0];
                    #pragma unroll
                    for (int w = 0; w < 8; ++w) { q0 += qpart[0][w][t]; q1 += qpart[1][w][t]; }
                    winsS[t] = (q0 <= q1) ? 0 : 1;
                }
            }
            __syncthreads();                          // B3: g1 (+ winsS) ready

            // ---- score (ungated rows): g1 @ w1x (8-iter, unroll 1 + dbuf) ----
            {
                f4 sa = (f4){0,0,0,0};
                const unsigned short* xp = w1x + (size_t)(ch*16 + mp)*256 + q*8;
                bf8 bx = *(const bf8*)xp;
                #pragma unroll 1
                for (int k0 = 0; k0 < 256; k0 += 32) {
                    bf8 nx = bx;
                    if (k0 + 32 < 256) nx = *(const bf8*)(xp + k0 + 32);
                    bf8 aa = *(const bf8*)&hbuf[(mt*16 + mp)*264 + k0 + q*8];
                    sa = MFMA(aa, bx, sa);
                    bx = nx;
                }
                if (net == 0) sa0 = sa; else sa1 = sa;
            }
            __syncthreads();                          // B4: g1 reads done
        } // net

        // ---- row-gated score select + S shadows; XT + norms ----
        {
            int colD = ch*16 + mp;               // 0..31 (cols >=20 exact zeros)
            #pragma unroll
            for (int r = 0; r < 4; ++r) {
                int row = mt*16 + q*4 + r, st = row >> 5, il = row & 31;
                float sv = winsS[row] ? sa1[r] : sa0[r];
                short sb = f2bfT(sv);
                SBs[row*32 + colD] = sb;
                STbS[st*1024 + colD*32 + il] = sb;
            }
        }
        if (t < 64) {
            int st = t >> 5, il = t & 31;
            float nrm = 0.f;
            #pragma unroll
            for (int d = 0; d < 20; ++d) {
                float xb = bf2f(A0s[t*96 + 64 + d]);
                nrm += xb * xb;
                XTbS[st*1024 + d*32 + il] = f2bfT(Xm[t*20 + d]);
            }
            #pragma unroll
            for (int d = 20; d < 32; ++d) XTbS[st*1024 + d*32 + il] = 0;
            normsS[t] = nrm;
        }
        __syncthreads();

        // ---- Gram: d2s = n_i+n_j-2*XX^T ; GS = X S^T ----
        {
            int stw = wv >> 2, mtl = (wv >> 1) & 1, ntl = wv & 1;
            bf8 aa  = *(const bf8*)&A0s[(stw*32 + mtl*16 + mp)*96 + 64 + q*8];
            bf8 bbx = *(const bf8*)&A0s[(stw*32 + ntl*16 + mp)*96 + 64 + q*8];
            bf8 bbs = *(const bf8*)&SBs[(stw*32 + ntl*16 + mp)*32 + q*8];
            f4 gx = MFMA(aa, bbx, ((f4){0,0,0,0}));
            f4 gs = MFMA(aa, bbs, ((f4){0,0,0,0}));
            int jl = ntl*16 + mp;
            float nj = normsS[stw*32 + jl];
            #pragma unroll
            for (int r = 0; r < 4; ++r) {
                int il = mtl*16 + q*4 + r;
                d2sF[stw*1024 + il*32 + jl] = normsS[stw*32 + il] + nj - 2.f*gx[r];
                GSF [stw*1024 + il*32 + jl] = gs[r];
            }
        }
        __syncthreads();

        // ---- median sort (waves 0-1, in-register bitonic) ----
        if (wv < 2) {
            const float* base = d2sF + wv*1024;
            float v[8];
            #pragma unroll
            for (int i = 0; i < 8; ++i) {
                int e = lane*8 + i;
                v[i] = (e < 496) ? base[lutI[e]*32 + lutJ[e]] : 3.4e38f;
            }
            for (int k = 2; k <= 512; k <<= 1) {
                for (int jj = k >> 1; jj >= 8; jj >>= 1) {
                    int lm = jj >> 3;
                    #pragma unroll
                    for (int i = 0; i < 8; ++i) {
                        float w = __shfl_xor(v[i], lm, 64);
                        int p = lane*8 + i;
                        bool takeMin = (((p & k) == 0) == ((p & jj) == 0));
                        v[i] = takeMin ? fminf(v[i], w) : fmaxf(v[i], w);
                    }
                }
                int jj0 = (k >> 1) < 4 ? (k >> 1) : 4;
                for (int jj = jj0; jj >= 1; jj >>= 1) {
                    #pragma unroll
                    for (int i = 0; i < 8; ++i) {
                        if ((i & jj) == 0) {
                            int i2 = i | jj;
                            int p = lane*8 + i;
                            bool up = ((p & k) == 0);
                            float x = v[i], y = v[i2];
                            float mn = fminf(x, y), mx = fmaxf(x, y);
                            v[i] = up ? mn : mx; v[i2] = up ? mx : mn;
                        }
                    }
                }
            }
            if (lane == 29) med2[wv*2 + 0] = v[7];   // sorted index 239
            if (lane == 30) med2[wv*2 + 1] = v[0];   // sorted index 240
        }
        __syncthreads();

        // ---- K = exp(-g d2), logp row-terms, rowK ----
        {
            int i = t >> 3, stw = i >> 5, il = i & 31, j0 = (t & 7) * 4;
            float medv = 0.5f * (med2[stw*2] + med2[stw*2 + 1]);
            float gam  = 1.f / (2.f * (medv / (2.f * LOG33)) + 1e-8f);
            float sK = 0.f, sKGS = 0.f, sKd2 = 0.f, sKdg = 0.f;
            #pragma unroll
            for (int jj = 0; jj < 4; ++jj) {
                int j = j0 + jj;
                float d2 = d2sF[stw*1024 + il*32 + j];
                float K  = expf(-gam * d2);
                KbS[stw*1024 + il*32 + j] = f2bfT(K);
                sK   += K;
                sKGS += K * GSF[stw*1024 + il*32 + j];
                sKd2 += K * d2;
                sKdg += K * GSF[stw*1024 + j*32 + j];   // diag GS_jj = x_j·s_j
            }
            #pragma unroll
            for (int d = 1; d < 8; d <<= 1) {
                sK   += __shfl_xor(sK,   d, 64);
                sKGS += __shfl_xor(sKGS, d, 64);
                sKd2 += __shfl_xor(sKd2, d, 64);
                sKdg += __shfl_xor(sKdg, d, 64);
            }
            if ((t & 7) == 0) {
                rowKS[i] = sK;
                float sdots = sKGS - sKdg;
                float ssum  = -2.f*gam*sdots
                              - 2.f*gam*(2.f*gam*sKd2 - 20.f*(sK - 1.f));
                logps[i] -= LRC * (ssum * (1.f/32.f));
            }
        }
        __syncthreads();

        // ---- phi = (K@S + 2g(x*rowK - K@X))/32 ; X += LR*phi ----
        {
            int stw = wv >> 2, mtl = (wv >> 1) & 1, ntl = wv & 1;
            float medv = 0.5f * (med2[stw*2] + med2[stw*2 + 1]);
            float gam  = 1.f / (2.f * (medv / (2.f * LOG33)) + 1e-8f);
            bf8 aa  = *(const bf8*)&KbS [stw*1024 + (mtl*16 + mp)*32 + q*8];
            bf8 b1v = *(const bf8*)&STbS[stw*1024 + (ntl*16 + mp)*32 + q*8];
            bf8 b2v = *(const bf8*)&XTbS[stw*1024 + (ntl*16 + mp)*32 + q*8];
            f4 ks = MFMA(aa, b1v, ((f4){0,0,0,0}));
            f4 kx = MFMA(aa, b2v, ((f4){0,0,0,0}));
            int dd = ntl*16 + mp;
            if (dd < 20) {
                #pragma unroll
                for (int r = 0; r < 4; ++r) {
                    int gi = stw*32 + mtl*16 + q*4 + r;
                    float xi  = Xm[gi*20 + dd];
                    float phi = (ks[r] + 2.f*gam*(xi*rowKS[gi] - kx[r])) * (1.f/32.f);
                    float nx  = xi + LRC * phi;
                    Xm[gi*20 + dd] = nx;
                    A0s[gi*96 + 64 + dd] = f2bfT(nx);
                }
            }
        }
        __syncthreads();
    } // steps

    // ================= epilogue =================
    for (int p = t; p < 64*20; p += 512) {
        int i = p / 20, d = p - i*20;
        out[(b*64 + i)*20 + d] = tanhf(Xm[p]);
    }
    if (t < 64) {
        float lt = 0.f, s0 = 0.f;
        for (int d = 0; d < 20; ++d) {
            float a  = Xm[t*20 + d];
            float x  = -2.f * a;
            float sp = fmaxf(x, 0.f) + log1pf(expf(-fabsf(x)));
            lt -= 2.f * (0.69314718056f - a - sp);
            float v = a0g[(b*64 + t)*20 + d];
            s0 += v * v;
        }
        qvS[t] = -18.3787706641f - 0.5f*s0 + logps[t] + lt;
    }
    __syncthreads();
    if (t < 2) {
        float s = 0.f;
        for (int i = 0; i < 32; ++i) s += qvS[t*32 + i];
        out[1024*32*20 + b*2 + t] = s * (1.f/32.f);
    }
}

extern "C" void kernel_launch(void* const* d_in, const int* in_sizes, int n_in,
                              void* d_out, int out_size, void* d_ws, size_t ws_size,
                              hipStream_t stream) {
    unsigned short* ws = (unsigned short*)d_ws;
    prep_weights<<<(WS_ELEMS + 255)/256, 256, 0, stream>>>(
        (const float*)d_in[2],  (const float*)d_in[4],  (const float*)d_in[6],
        (const float*)d_in[8],  (const float*)d_in[10], (const float*)d_in[12], ws);
    svgd_main<<<NBLK, 512, 0, stream>>>(
        (const float*)d_in[0],  (const float*)d_in[1],
        (const float*)d_in[3],  (const float*)d_in[5],  (const float*)d_in[7],
        (const float*)d_in[9],  (const float*)d_in[11], (const float*)d_in[13],
        (const float*)d_in[6],  (const float*)d_in[12],
        ws, (float*)d_out);
}